// Round 9
// baseline (368.143 us; speedup 1.0000x reference)
//
#include <hip/hip_runtime.h>
#include <hip/hip_bf16.h>
#include <cstddef>
#include <math.h>

// Problem constants (from reference)
#define N_NODES 16384   // B*A
#define DIN 64
#define HID 128
#define SCALE_F 0.17677669529663687f  // 1/sqrt(32)

using bf16x8 = __attribute__((ext_vector_type(8))) short;   // 8 bf16 = 4 VGPRs
using f32x4  = __attribute__((ext_vector_type(4))) float;   // MFMA acc

__device__ __forceinline__ ushort f2b(float x) {
  __hip_bfloat16 h = __float2bfloat16(x);
  return *(ushort*)&h;
}
__device__ __forceinline__ float b2f(ushort u) {
  __hip_bfloat16 h = *(__hip_bfloat16*)&u;
  return __bfloat162float(h);
}
// fp32 -> 2-way split (hi+lo), err ~2^-17 |x|
__device__ __forceinline__ void split1(float x, ushort& h, ushort& l) {
  h = f2b(x);
  l = f2b(x - b2f(h));
}
// fp32 -> 3-way split (a+b+c), err ~2^-27 |x|  (F/M path, proven)
__device__ __forceinline__ void split3(float x, ushort& a, ushort& b, ushort& c) {
  a = f2b(x);
  float r1 = x - b2f(a);
  b = f2b(r1);
  c = f2b(r1 - b2f(b));
}

#define MFMA(d, A, B) d = __builtin_amdgcn_mfma_f32_16x16x32_bf16(A, B, d, 0, 0, 0)

// ---------------- merged prep: G, M0, M1, W1/W2 splits, zero(out) ----------------
// R18: vectorized (4 outputs/thread, float4 loads); bit-identical M.
// block ranges: [0] G | [1,33) M0 | [33,97) M1 | [97,129) W1 | [129,193) W2
//               | [193,225) zero

__global__ __launch_bounds__(256) void prep_all_kernel(
    const float* __restrict__ Wq0, const float* __restrict__ Wk0,
    const float* __restrict__ Wq1, const float* __restrict__ Wk1,
    float* __restrict__ G,
    const float* __restrict__ Wv0, const float* __restrict__ Wo0,
    ushort* __restrict__ M0a, ushort* __restrict__ M0b, ushort* __restrict__ M0c,
    const float* __restrict__ Wv1, const float* __restrict__ Wo1,
    ushort* __restrict__ M1a, ushort* __restrict__ M1b, ushort* __restrict__ M1c,
    const float* __restrict__ W1, ushort* __restrict__ W1hi, ushort* __restrict__ W1lo,
    const float* __restrict__ W2, ushort* __restrict__ W2hi, ushort* __restrict__ W2lo,
    unsigned long long* __restrict__ out64)
{
  int blk = blockIdx.x, t = threadIdx.x;
  if (blk == 0) {
    if (t >= 32) return;
    int l = t >> 4, h = (t >> 2) & 3, a = (t >> 1) & 1, b = t & 1;
    const float* Wq = l ? Wq1 : Wq0;
    const float* Wk = l ? Wk1 : Wk0;
    float acc = 0.f;
    for (int c = 0; c < 128; c++)
      acc += Wq[(h * 128 + c) * 2 + a] * Wk[(h * 128 + c) * 2 + b];
    G[t] = acc;
  } else if (blk < 97) {
    // folded M = Wv^T-contract-Wo, triple-split; 4 consecutive d per thread.
    int D, gidx;
    const float *Wv, *Wo;
    ushort *Ma, *Mb, *Mc;
    if (blk < 33) { D = DIN; gidx = (blk - 1) * 256 + t;  Wv = Wv0; Wo = Wo0; Ma = M0a; Mb = M0b; Mc = M0c; }
    else          { D = HID; gidx = (blk - 33) * 256 + t; Wv = Wv1; Wo = Wo1; Ma = M1a; Mb = M1b; Mc = M1c; }
    int o = gidx / D, rem = gidx - o * D;          // D groups of 4 per o-row
    int qD = D >> 2;
    int h = rem / qD, d0 = (rem - h * qD) * 4;
    const float* wv = Wv + (size_t)(h * 128) * D + d0;
    const float* wo = Wo + (size_t)o * 512 + h * 128;
    float ax = 0.f, ay = 0.f, az = 0.f, aw = 0.f;
    for (int c = 0; c < 128; c++) {
      float4 v = *(const float4*)&wv[(size_t)c * D];
      float w = wo[c];
      ax += v.x * w; ay += v.y * w; az += v.z * w; aw += v.w * w;
    }
    int idx = o * (4 * D) + h * D + d0;
    ushort4 ua, ub, uc;
    split3(ax, ua.x, ub.x, uc.x);
    split3(ay, ua.y, ub.y, uc.y);
    split3(az, ua.z, ub.z, uc.z);
    split3(aw, ua.w, ub.w, uc.w);
    *(ushort4*)&Ma[idx] = ua;
    *(ushort4*)&Mb[idx] = ub;
    *(ushort4*)&Mc[idx] = uc;
  } else if (blk < 193) {
    if (blk < 129) {
      int i = ((blk - 97) * 256 + t) * 4;          // 32768 = 256*128 elems
      float4 w = *(const float4*)&W1[i];
      ushort4 hi, lo;
      split1(w.x, hi.x, lo.x); split1(w.y, hi.y, lo.y);
      split1(w.z, hi.z, lo.z); split1(w.w, hi.w, lo.w);
      *(ushort4*)&W1hi[i] = hi;
      *(ushort4*)&W1lo[i] = lo;
    } else {
      int j = ((blk - 129) * 256 + t) * 4;         // 65536 = 256*256 elems
      float4 w = *(const float4*)&W2[j];
      ushort4 hi, lo;
      split1(w.x, hi.x, lo.x); split1(w.y, hi.y, lo.y);
      split1(w.z, hi.z, lo.z); split1(w.w, hi.w, lo.w);
      *(ushort4*)&W2hi[j] = hi;
      *(ushort4*)&W2lo[j] = lo;
    }
  } else {
    int i = (blk - 193) * 256 + t;                 // 8192 float4 = 16384 u64
    ((float4*)out64)[i] = (float4){0.f, 0.f, 0.f, 0.f};
  }
}

// ---------------- fully fused: mask build + 2-layer GAT + 3-layer MLP ----------------
// R21: y-redistribute via wave-private LDS bounce. The C-layout -> B-frag
// conversion used 32 ds_bpermute + 16 selects per head (128 bpermute/wave) --
// serial glue between each head's two MFMA groups. Now: write y tiles as
// float4 (C-layout lane = 4 consecutive n at fixed o -> b128) into the
// wave's private 2KB slice of the part region (idle during gat_layer; each
// wave's slice == its boundary-exchange block, bijective), read back 8
// consecutive n per lane (2x b128) in exactly B-frag order, split1 as
// before. 4-word XOR swizzle (n ^= (lm&7)<<2) keeps accesses <=2-way (free).
// Same-wave DS ops are ordered; region private -> no new barriers. f32
// store/load exact -> bit-identical. R20's balanced ship/combine kept.

// LDS layout (ushort offsets), total 74240 ushorts = 148480 B:
//  sFa 0 | sFb 8192 | sFc 16384   (64x128 each, swizzled)
//  pxs 24576 (f32[64]) | pys 24704 (f32[64]) | smask 24832 (u64[64])
//  aA 25088 (32768 ushorts = 64KB, 16 A-frag pairs)   [MLP: pA=aA, pB=aA+16384]
//  PART 57856 (16384 ushorts = 32KB: 16 blocks x 512 f32; per-wave yT slice
//              during gat_layer, pair-exchange slots at layer boundaries)
#define SFB_OFF 8192
#define SFC_OFF 16384
#define PXS_OFF 24576
#define PYS_OFF 24704
#define SMASK_OFF 24832
#define AFRAG_OFF 25088
#define PART_OFF 57856
#define LDS_USHORTS 74240

// A-build for one (h,mtd) pair: wave-agnostic (lane x pairid only).
__device__ __forceinline__ void build_A(
    int pairid, int lane, int lm, int lq, ushort* aA,
    const float* pxs, const float* pys,
    const unsigned long long* smask, const float* __restrict__ G)
{
  int wm = pairid & 3;
  int h = pairid >> 2;
  float pdxm = pxs[wm * 16 + lm];
  float pdym = pys[wm * 16 + lm];
  unsigned long long mm = smask[wm * 16 + lm];
  unsigned mb0 = (unsigned)((mm >> (8 * lq)) & 0xFF);
  unsigned mb1 = (unsigned)((mm >> (32 + 8 * lq)) & 0xFF);
  float g0 = G[h * 4], g1 = G[h * 4 + 1], g2 = G[h * 4 + 2], g3 = G[h * 4 + 3];
  float a0 = (g0 * pdxm + g2 * pdym) * SCALE_F;
  float a1 = (g1 * pdxm + g3 * pdym) * SCALE_F;
  float sshift = a0 * pdxm + a1 * pdym;
  float e[16];
  float sum = 0.f;
#pragma unroll
  for (int j = 0; j < 8; j++) {
    e[j]     = ((mb0 >> j) & 1) ? __expf(a0 * pxs[8 * lq + j] + a1 * pys[8 * lq + j] - sshift) : 0.f;
    e[8 + j] = ((mb1 >> j) & 1) ? __expf(a0 * pxs[32 + 8 * lq + j] + a1 * pys[32 + 8 * lq + j] - sshift) : 0.f;
    sum += e[j] + e[8 + j];
  }
  sum += __shfl_xor(sum, 16);
  sum += __shfl_xor(sum, 32);
  float inv = 1.f / sum;
  bf16x8 Aa0, Aa1, Ab0, Ab1;
#pragma unroll
  for (int j = 0; j < 8; j++) {
    ushort ua, ub;
    split1(e[j] * inv, ua, ub);     Aa0[j] = (short)ua; Ab0[j] = (short)ub;
    split1(e[8 + j] * inv, ua, ub); Aa1[j] = (short)ua; Ab1[j] = (short)ub;
  }
  int sbase = pairid * 2048 + lane * 8;
  *(bf16x8*)&aA[sbase]        = Aa0;
  *(bf16x8*)&aA[sbase + 512]  = Aa1;
  *(bf16x8*)&aA[sbase + 1024] = Ab0;
  *(bf16x8*)&aA[sbase + 1536] = Ab1;
}

template <int KD, bool BUILD_A>
__device__ __forceinline__ void gat_layer(
    int wave, int lane, int lm, int lq,
    const ushort* sFa, const ushort* sFb, const ushort* sFc,
    ushort* aA, float* yT,
    const float* pxs, const float* pys,
    const unsigned long long* smask,
    const float* __restrict__ G,
    const ushort* __restrict__ Ma, const ushort* __restrict__ Mb,
    const ushort* __restrict__ Mc,
    bf16x8 nA, bf16x8 nB, bf16x8 nC,    // prologue M triple (hoisted by caller)
    f32x4 hacc[4])
{
  constexpr int NKF = KD / 32;
  const int K4 = 4 * KD;
  const int o = 16 * (wave & 7) + lm;
  const int hb = wave >> 3;

  if (BUILD_A) {
    // layer-0 path: every wave builds its own pair, then barrier.
    build_A(wave, lane, lm, lq, aA, pxs, pys, smask, G);
    __syncthreads();   // BA: all 16 pairs' A-frags visible
  }
  // layer-1 path (BUILD_A=false): A-frags were built in the B3->B4 window
  // (1 pair per wave); caller's B4 barrier provides write->read ordering.

#pragma unroll
  for (int i = 0; i < 4; i++) hacc[i] = (f32x4){0.f, 0.f, 0.f, 0.f};

#pragma unroll 1
  for (int hi = 0; hi < 2; hi++) {
    int h = 2 * hb + hi;     // waves 0-7: heads {0,1}; waves 8-15: heads {2,3}
    f32x4 y[4];
#pragma unroll
    for (int i = 0; i < 4; i++) y[i] = (f32x4){0.f, 0.f, 0.f, 0.f};
#pragma unroll 1
    for (int kf = 0; kf < NKF; kf++) {
      int ko = kf * 32 + lq * 8;
      int sw = lm << 3;
      bf16x8 ma = nA, mb = nB, mc = nC;   // consume current triple
#pragma unroll
      for (int mp = 0; mp < 2; mp++) {
        int f0 = (mp * 32 + lm) * 128 + (ko ^ sw);
        int f1 = f0 + 16 * 128;
        bf16x8 fa0 = *(const bf16x8*)&sFa[f0], fa1 = *(const bf16x8*)&sFa[f1];
        bf16x8 fb0 = *(const bf16x8*)&sFb[f0], fb1 = *(const bf16x8*)&sFb[f1];
        bf16x8 fc0 = *(const bf16x8*)&sFc[f0], fc1 = *(const bf16x8*)&sFc[f1];
        f32x4 y0 = y[mp * 2], y1 = y[mp * 2 + 1];
        MFMA(y0, fa0, ma); MFMA(y1, fa1, ma);
        MFMA(y0, fa0, mb); MFMA(y1, fa1, mb);
        MFMA(y0, fb0, ma); MFMA(y1, fb1, ma);
        MFMA(y0, fa0, mc); MFMA(y1, fa1, mc);
        MFMA(y0, fc0, ma); MFMA(y1, fc1, ma);
        MFMA(y0, fb0, mb); MFMA(y1, fb1, mb);
        y[mp * 2] = y0; y[mp * 2 + 1] = y1;
      }
      // refill: next kf of this head, or kf=0 of head h+1 (skip at very end).
      if (hi == 0 || kf != NKF - 1) {
        int hn = (kf == NKF - 1) ? (h + 1) : h;
        int kn = (kf == NKF - 1) ? 0 : (kf + 1);
        size_t boff = (size_t)o * K4 + hn * KD + kn * 32 + lq * 8;
        nA = *(const bf16x8*)&Ma[boff];
        nB = *(const bf16x8*)&Mb[boff];
        nC = *(const bf16x8*)&Mc[boff];
      }
    }
    // redistribute y (C-layout) -> B-frag values via wave-private LDS bounce.
    // Write: y[2kb+t] = rows n_local = t*16+lq*4..+3 at col o=lm -> float4.
    // Read:  lane needs n_local = lq*8..+7 at col o=lm -> 2x float4.
    // XOR swizzle at 4-word granularity keeps both <=2-way bank-aliased.
    // Same-wave DS ordering handles the kb=0 read / kb=1 write reuse.
    bf16x8 Ya[2], Yb[2];
    int swz = (lm & 7) << 2;
#pragma unroll 1
    for (int kb = 0; kb < 2; kb++) {
#pragma unroll
      for (int tt = 0; tt < 2; tt++) {
        int nl = tt * 16 + lq * 4;
        *(float4*)&yT[lm * 32 + (nl ^ swz)] = *(float4*)&y[2 * kb + tt];
      }
      float4 r0 = *(const float4*)&yT[lm * 32 + ((lq * 8) ^ swz)];
      float4 r1 = *(const float4*)&yT[lm * 32 + ((lq * 8 + 4) ^ swz)];
      float rv[8] = {r0.x, r0.y, r0.z, r0.w, r1.x, r1.y, r1.z, r1.w};
#pragma unroll
      for (int j = 0; j < 8; j++) {
        ushort ua, ub;
        split1(rv[j], ua, ub);
        Ya[kb][j] = (short)ua; Yb[kb][j] = (short)ub;
      }
    }
    // A@Y per dst tile, A-frags from LDS (lane-linear b128, conflict-free)
#pragma unroll
    for (int mtd = 0; mtd < 4; mtd++) {
      int abase = (h * 4 + mtd) * 2048 + lane * 8;
      bf16x8 Aa0 = *(const bf16x8*)&aA[abase];
      bf16x8 Aa1 = *(const bf16x8*)&aA[abase + 512];
      bf16x8 Ab0 = *(const bf16x8*)&aA[abase + 1024];
      bf16x8 Ab1 = *(const bf16x8*)&aA[abase + 1536];
      MFMA(hacc[mtd], Aa0, Ya[0]);
      MFMA(hacc[mtd], Aa0, Yb[0]);
      MFMA(hacc[mtd], Ab0, Ya[0]);
      MFMA(hacc[mtd], Ab0, Yb[0]);
      MFMA(hacc[mtd], Aa1, Ya[1]);
      MFMA(hacc[mtd], Aa1, Yb[1]);
      MFMA(hacc[mtd], Ab1, Ya[1]);
      MFMA(hacc[mtd], Ab1, Yb[1]);
    }
  }
}

__global__ __attribute__((amdgpu_flat_work_group_size(1024, 1024), amdgpu_waves_per_eu(4, 4)))
void fused_gat_kernel(
    const float* __restrict__ x, const float* __restrict__ pos,
    const int* __restrict__ srcp, const int* __restrict__ dstp,
    const float* __restrict__ G,
    const ushort* __restrict__ M0a, const ushort* __restrict__ M0b, const ushort* __restrict__ M0c,
    const ushort* __restrict__ M1a, const ushort* __restrict__ M1b, const ushort* __restrict__ M1c,
    const float* __restrict__ bo0, const float* __restrict__ bo1,
    const ushort* __restrict__ W1hi, const ushort* __restrict__ W1lo, const float* __restrict__ b1,
    const ushort* __restrict__ W2hi, const ushort* __restrict__ W2lo, const float* __restrict__ b2,
    const float* __restrict__ W3, const float* __restrict__ b3,
    float* __restrict__ outp)
{
  __shared__ __align__(16) ushort uBig[LDS_USHORTS];
  ushort* sFa = uBig;
  ushort* sFb = uBig + SFB_OFF;
  ushort* sFc = uBig + SFC_OFF;
  float* pxs = (float*)(uBig + PXS_OFF);
  float* pys = (float*)(uBig + PYS_OFF);
  unsigned long long* smask = (unsigned long long*)(uBig + SMASK_OFF);
  ushort* aA = uBig + AFRAG_OFF;
  ushort* pA = uBig + AFRAG_OFF;            // MLP reuse of A region (dead by then)
  ushort* pB = uBig + AFRAG_OFF + 16384;
  float* part = (float*)(uBig + PART_OFF);  // 16 x 512-f32 wave blocks

  int b = blockIdx.x, t = threadIdx.x;
  int wave = t >> 6, lane = t & 63, lm = lane & 15, lq = lane >> 4;
  int o = 16 * (wave & 7) + lm;

  // per-wave block (yT slice == own exchange slot); partner block for reads
  int half = wave >> 3;
  float* yT = part + (2 * (wave & 7) + half) * 512;
  const float* pT = part + (2 * (wave & 7) + (1 - half)) * 512;

  // ---- hoisted global loads: edges, pos, x, biases, layer-0 M prologue ----
  int e_s = 0, e_d = 0;
  if (t < 448) {
    e_s = srcp[b * 448 + t];
    e_d = dstp[b * 448 + t];
  }
  float posx = 0.f, posy = 0.f;
  if (t < 64) {
    posx = pos[(b * 64 + t) * 2];
    posy = pos[(b * 64 + t) * 2 + 1];
  }
  const float4* gx = (const float4*)(x + (size_t)b * 64 * DIN);
  float4 xv = gx[t];
  float bv0 = bo0[o];
  float bv1 = bo1[o];
  // layer-0 M prologue triple (head 2*half, kf 0); in flight across
  // X-staging + B1 + mask + B2 + A-build.
  bf16x8 m0A, m0B, m0C;
  {
    size_t boff = (size_t)o * (4 * DIN) + (half * 2) * DIN + lq * 8;
    m0A = *(const bf16x8*)&M0a[boff];
    m0B = *(const bf16x8*)&M0b[boff];
    m0C = *(const bf16x8*)&M0c[boff];
  }

  if (t < 64) {
    pxs[t] = posx;
    pys[t] = posy;
    smask[t] = 1ull << t;   // self-loop bit
  }
  // stage X (64x64 fp32) -> triple-split swizzled planes; one float4/thread
  {
    int r = t >> 4, c = (t & 15) * 4;
    int cs = c ^ ((r & 15) << 3);
    ushort4 ua, ub, uc;
    split3(xv.x, ua.x, ub.x, uc.x); split3(xv.y, ua.y, ub.y, uc.y);
    split3(xv.z, ua.z, ub.z, uc.z); split3(xv.w, ua.w, ub.w, uc.w);
    *(ushort4*)&sFa[r * 128 + cs] = ua;
    *(ushort4*)&sFb[r * 128 + cs] = ub;
    *(ushort4*)&sFc[r * 128 + cs] = uc;
  }
  __syncthreads();   // B1: smask init + X visible
  // adjacency from this block's own 448 kNN edge rows (loads hoisted to top)
  if (t < 448) {
    atomicOr(&smask[e_d & 63], 1ull << (e_s & 63));
  }
  __syncthreads();   // B2

  f32x4 hacc[4];
  gat_layer<DIN, true>(wave, lane, lm, lq, sFa, sFb, sFc, aA, yT, pxs, pys,
                       smask, G, M0a, M0b, M0c, m0A, m0B, m0C, hacc);

  // layer-1 M prologue; in flight across exchange / B3 / combine / B4
  bf16x8 m1A, m1B, m1C;
  {
    size_t boff = (size_t)o * (4 * HID) + (half * 2) * HID + lq * 8;
    m1A = *(const bf16x8*)&M1a[boff];
    m1B = *(const bf16x8*)&M1b[boff];
    m1C = *(const bf16x8*)&M1c[boff];
  }

  // ship the 2 dst-tiles the partner combines (b128 each, own block)
  if (wave < 8) {
    *(float4*)&yT[lane * 4]       = *(float4*)&hacc[2];
    *(float4*)&yT[lane * 4 + 256] = *(float4*)&hacc[3];
  } else {
    *(float4*)&yT[lane * 4]       = *(float4*)&hacc[0];
    *(float4*)&yT[lane * 4 + 256] = *(float4*)&hacc[1];
  }
  __syncthreads();   // B3: layer-0 F/A reads done + partials visible
  {
    // balanced combine: every wave activates 2 dst-tiles + builds 1 layer-1
    // A-pair. Sum order: own + partner == commutative swap -> bit-identical.
    float4 q0 = *(const float4*)&pT[lane * 4];
    float4 q1 = *(const float4*)&pT[lane * 4 + 256];
    float pr0[4] = {q0.x, q0.y, q0.z, q0.w};
    float pr1[4] = {q1.x, q1.y, q1.z, q1.w};
    if (wave < 8) {
#pragma unroll
      for (int r = 0; r < 4; r++) {
        int d0 = lq * 4 + r;
        float v = tanhf(hacc[0][r] + pr0[r] + bv0);
        ushort ua, ub, uc;
        split3(v, ua, ub, uc);
        int cs = o ^ ((d0 & 15) << 3);
        sFa[d0 * 128 + cs] = ua; sFb[d0 * 128 + cs] = ub; sFc[d0 * 128 + cs] = uc;
        int d1 = 16 + lq * 4 + r;
        v = tanhf(hacc[1][r] + pr1[r] + bv0);
        split3(v, ua, ub, uc);
        sFa[d1 * 128 + cs] = ua; sFb[d1 * 128 + cs] = ub; sFc[d1 * 128 + cs] = uc;
      }
    } else {
#pragma unroll
      for (int r = 0; r < 4; r++) {
        int d2 = 32 + lq * 4 + r;
        float v = tanhf(hacc[2][r] + pr0[r] + bv0);
        ushort ua, ub, uc;
        split3(v, ua, ub, uc);
        int cs = o ^ ((d2 & 15) << 3);
        sFa[d2 * 128 + cs] = ua; sFb[d2 * 128 + cs] = ub; sFc[d2 * 128 + cs] = uc;
        int d3 = 48 + lq * 4 + r;
        v = tanhf(hacc[3][r] + pr1[r] + bv0);
        split3(v, ua, ub, uc);
        sFa[d3 * 128 + cs] = ua; sFb[d3 * 128 + cs] = ub; sFc[d3 * 128 + cs] = uc;
      }
    }
    build_A(wave, lane, lm, lq, aA, pxs, pys, smask, G + 16);
  }
  __syncthreads();   // B4: h1 planes + layer-1 A-frags visible
  gat_layer<HID, false>(wave, lane, lm, lq, sFa, sFb, sFc, aA, yT, pxs, pys,
                        smask, G + 16, M1a, M1b, M1c, m1A, m1B, m1C, hacc);

  // prefetch W1 frags + b1 now; in flight across exchange / B5 / combine / B6
  int col = 16 * wave + lm;
  bf16x8 pw1h[4], pw1l[4];
#pragma unroll
  for (int kf = 0; kf < 4; kf++) {
    int ko = kf * 32 + lq * 8;
    pw1h[kf] = *(const bf16x8*)&W1hi[(size_t)col * 128 + ko];
    pw1l[kf] = *(const bf16x8*)&W1lo[(size_t)col * 128 + ko];
  }
  float b1v = b1[col];

  if (wave < 8) {
    *(float4*)&yT[lane * 4]       = *(float4*)&hacc[2];
    *(float4*)&yT[lane * 4 + 256] = *(float4*)&hacc[3];
  } else {
    *(float4*)&yT[lane * 4]       = *(float4*)&hacc[0];
    *(float4*)&yT[lane * 4 + 256] = *(float4*)&hacc[1];
  }
  __syncthreads();   // B5
  {
    float4 q0 = *(const float4*)&pT[lane * 4];
    float4 q1 = *(const float4*)&pT[lane * 4 + 256];
    float pr0[4] = {q0.x, q0.y, q0.z, q0.w};
    float pr1[4] = {q1.x, q1.y, q1.z, q1.w};
    if (wave < 8) {
#pragma unroll
      for (int r = 0; r < 4; r++) {
        int d0 = lq * 4 + r;
        float v = tanhf(hacc[0][r] + pr0[r] + bv1);
        ushort hh, ll;
        split1(v, hh, ll);
        int cs = o ^ ((d0 & 15) << 3);
        sFa[d0 * 128 + cs] = hh; sFb[d0 * 128 + cs] = ll;
        int d1 = 16 + lq * 4 + r;
        v = tanhf(hacc[1][r] + pr1[r] + bv1);
        split1(v, hh, ll);
        sFa[d1 * 128 + cs] = hh; sFb[d1 * 128 + cs] = ll;
      }
    } else {
#pragma unroll
      for (int r = 0; r < 4; r++) {
        int d2 = 32 + lq * 4 + r;
        float v = tanhf(hacc[2][r] + pr0[r] + bv1);
        ushort hh, ll;
        split1(v, hh, ll);
        int cs = o ^ ((d2 & 15) << 3);
        sFa[d2 * 128 + cs] = hh; sFb[d2 * 128 + cs] = ll;
        int d3 = 48 + lq * 4 + r;
        v = tanhf(hacc[3][r] + pr1[r] + bv1);
        split1(v, hh, ll);
        sFa[d3 * 128 + cs] = hh; sFb[d3 * 128 + cs] = ll;
      }
    }
  }
  __syncthreads();   // B6
  // ---- W1: out1 = relu(h2 @ W1^T + b1); 16 waves x 16 cols ----
  f32x4 y1[4];
#pragma unroll
  for (int mtd = 0; mtd < 4; mtd++) y1[mtd] = (f32x4){0.f, 0.f, 0.f, 0.f};
#pragma unroll
  for (int kf = 0; kf < 4; kf++) {
    int ko = kf * 32 + lq * 8;
    bf16x8 bh = pw1h[kf];
    bf16x8 bl = pw1l[kf];
#pragma unroll
    for (int mtd = 0; mtd < 4; mtd++) {
      int row = mtd * 16 + lm;
      int cs = ko ^ (lm << 3);
      bf16x8 ah = *(const bf16x8*)&sFa[row * 128 + cs];
      bf16x8 al = *(const bf16x8*)&sFb[row * 128 + cs];
      MFMA(y1[mtd], ah, bh);
      MFMA(y1[mtd], ah, bl);
      MFMA(y1[mtd], al, bh);
    }
  }
  // store out1 split2, XOR-swizzled: elem (row,k) at row*256 + (k ^ ((row&15)<<3))
  {
#pragma unroll
    for (int mtd = 0; mtd < 4; mtd++)
#pragma unroll
      for (int r = 0; r < 4; r++) {
        int row = mtd * 16 + lq * 4 + r;
        float v = fmaxf(y1[mtd][r] + b1v, 0.f);
        ushort hh, ll;
        split1(v, hh, ll);
        int cc = col ^ ((row & 15) << 3);
        pA[row * 256 + cc] = hh;
        pB[row * 256 + cc] = ll;
      }
  }
  // prefetch W2 frags + W3/b2 scalars; in flight across B8
  bf16x8 pw2h[8], pw2l[8];
#pragma unroll
  for (int kf = 0; kf < 8; kf++) {
    int ko = kf * 32 + lq * 8;
    pw2h[kf] = *(const bf16x8*)&W2hi[(size_t)col * 256 + ko];
    pw2l[kf] = *(const bf16x8*)&W2lo[(size_t)col * 256 + ko];
  }
  float w30 = W3[col], w31 = W3[256 + col];
  float b20 = b2[col];
  float bb0 = (wave == 0) ? b3[0] : 0.f;
  float bb1 = (wave == 0) ? b3[1] : 0.f;
  __syncthreads();   // B8
  // ---- W2 + fused W3 ----
  f32x4 y2[4];
#pragma unroll
  for (int mtd = 0; mtd < 4; mtd++) y2[mtd] = (f32x4){0.f, 0.f, 0.f, 0.f};
#pragma unroll
  for (int kf = 0; kf < 8; kf++) {
    int ko = kf * 32 + lq * 8;
    bf16x8 bh = pw2h[kf];
    bf16x8 bl = pw2l[kf];
#pragma unroll
    for (int mtd = 0; mtd < 4; mtd++) {
      int row = mtd * 16 + lm;
      int cc = ko ^ (lm << 3);
      bf16x8 ah = *(const bf16x8*)&pA[row * 256 + cc];
      bf16x8 al = *(const bf16x8*)&pB[row * 256 + cc];
      MFMA(y2[mtd], ah, bh);
      MFMA(y2[mtd], ah, bl);
      MFMA(y2[mtd], al, bh);
    }
  }
  // W3 epilogue: per-row dot over this wave's 16 cols, lm-reduce, atomicAdd
  {
#pragma unroll
    for (int mtd = 0; mtd < 4; mtd++)
#pragma unroll
      for (int r = 0; r < 4; r++) {
        float va = fmaxf(y2[mtd][r] + b20, 0.f);
        float s0 = va * w30;
        float s1 = va * w31;
        s0 += __shfl_xor(s0, 1); s0 += __shfl_xor(s0, 2);
        s0 += __shfl_xor(s0, 4); s0 += __shfl_xor(s0, 8);
        s1 += __shfl_xor(s1, 1); s1 += __shfl_xor(s1, 2);
        s1 += __shfl_xor(s1, 4); s1 += __shfl_xor(s1, 8);
        if (lm == 0) {
          int row = b * 64 + mtd * 16 + lq * 4 + r;
          atomicAdd(&outp[row * 2 + 0], s0 + bb0);
          atomicAdd(&outp[row * 2 + 1], s1 + bb1);
        }
      }
  }
}

// ---------------- launch ----------------

extern "C" void kernel_launch(void* const* d_in, const int* in_sizes, int n_in,
                              void* d_out, int out_size, void* d_ws, size_t ws_size,
                              hipStream_t stream) {
  const float* x     = (const float*)d_in[0];
  const float* pos   = (const float*)d_in[1];
  const int*   ei    = (const int*)d_in[2];
  const float* l0_Wq = (const float*)d_in[3];
  const float* l0_Wk = (const float*)d_in[4];
  const float* l0_Wv = (const float*)d_in[5];
  const float* l0_Wo = (const float*)d_in[6];
  const float* l0_bo = (const float*)d_in[7];
  const float* l1_Wq = (const float*)d_in[8];
  const float* l1_Wk = (const float*)d_in[9];
  const float* l1_Wv = (const float*)d_in[10];
  const float* l1_Wo = (const float*)d_in[11];
  const float* l1_bo = (const float*)d_in[12];
  const float* W1    = (const float*)d_in[13];
  const float* b1    = (const float*)d_in[14];
  const float* W2    = (const float*)d_in[15];
  const float* b2    = (const float*)d_in[16];
  const float* W3    = (const float*)d_in[17];
  const float* b3    = (const float*)d_in[18];
  float* outp = (float*)d_out;

  int E = in_sizes[2] / 2;
  const int* srcp = ei;
  const int* dstp = ei + E;

  char* base = (char*)d_ws;
  size_t off = 0;
  auto alloc = [&](size_t bytes) -> void* {
    void* p = base + off;
    off = (off + bytes + 255) & ~(size_t)255;
    return p;
  };
  float*  G   = (float*)alloc(32 * sizeof(float));
  ushort* M0a = (ushort*)alloc((size_t)128 * 256 * 2);
  ushort* M0b = (ushort*)alloc((size_t)128 * 256 * 2);
  ushort* M0c = (ushort*)alloc((size_t)128 * 256 * 2);
  ushort* M1a = (ushort*)alloc((size_t)128 * 512 * 2);
  ushort* M1b = (ushort*)alloc((size_t)128 * 512 * 2);
  ushort* M1c = (ushort*)alloc((size_t)128 * 512 * 2);
  ushort* W1hi = (ushort*)alloc((size_t)256 * 128 * 2);
  ushort* W1lo = (ushort*)alloc((size_t)256 * 128 * 2);
  ushort* W2hi = (ushort*)alloc((size_t)256 * 256 * 2);
  ushort* W2lo = (ushort*)alloc((size_t)256 * 256 * 2);

  // prep: G, M folds (4-wide vectorized), W splits, zero(out). Grid 225.
  prep_all_kernel<<<225, 256, 0, stream>>>(
      l0_Wq, l0_Wk, l1_Wq, l1_Wk, G,
      l0_Wv, l0_Wo, M0a, M0b, M0c,
      l1_Wv, l1_Wo, M1a, M1b, M1c,
      W1, W1hi, W1lo, W2, W2hi, W2lo,
      (unsigned long long*)outp);

  // fully fused network: 1024 threads (16 waves), head-split halves
  fused_gat_kernel<<<N_NODES / 64, 1024, 0, stream>>>(
      x, pos, srcp, dstp, G, M0a, M0b, M0c, M1a, M1b, M1c, l0_bo, l1_bo,
      W1hi, W1lo, b1, W2hi, W2lo, b2, W3, b3, outp);

  (void)n_in; (void)out_size; (void)ws_size;
}

// Round 10
// 151.958 us; speedup vs baseline: 2.4227x; 2.4227x over previous
//
#include <hip/hip_runtime.h>
#include <hip/hip_bf16.h>
#include <cstddef>
#include <math.h>

// Problem constants (from reference)
#define N_NODES 16384   // B*A
#define DIN 64
#define HID 128
#define SCALE_F 0.17677669529663687f  // 1/sqrt(32)

using bf16x8 = __attribute__((ext_vector_type(8))) short;   // 8 bf16 = 4 VGPRs
using f32x4  = __attribute__((ext_vector_type(4))) float;   // MFMA acc

__device__ __forceinline__ ushort f2b(float x) {
  __hip_bfloat16 h = __float2bfloat16(x);
  return *(ushort*)&h;
}
__device__ __forceinline__ float b2f(ushort u) {
  __hip_bfloat16 h = *(__hip_bfloat16*)&u;
  return __bfloat162float(h);
}
// fp32 -> 2-way split (hi+lo), err ~2^-17 |x|
__device__ __forceinline__ void split1(float x, ushort& h, ushort& l) {
  h = f2b(x);
  l = f2b(x - b2f(h));
}
// fp32 -> 3-way split (a+b+c), err ~2^-27 |x|  (F/M path, proven)
__device__ __forceinline__ void split3(float x, ushort& a, ushort& b, ushort& c) {
  a = f2b(x);
  float r1 = x - b2f(a);
  b = f2b(r1);
  c = f2b(r1 - b2f(b));
}

#define MFMA(d, A, B) d = __builtin_amdgcn_mfma_f32_16x16x32_bf16(A, B, d, 0, 0, 0)

// ---------------- merged prep: G, M0, M1, W1/W2 splits, zero(out) ----------------
// R18: vectorized (4 outputs/thread, float4 loads); bit-identical M.
// block ranges: [0] G | [1,33) M0 | [33,97) M1 | [97,129) W1 | [129,193) W2
//               | [193,225) zero

__global__ __launch_bounds__(256) void prep_all_kernel(
    const float* __restrict__ Wq0, const float* __restrict__ Wk0,
    const float* __restrict__ Wq1, const float* __restrict__ Wk1,
    float* __restrict__ G,
    const float* __restrict__ Wv0, const float* __restrict__ Wo0,
    ushort* __restrict__ M0a, ushort* __restrict__ M0b, ushort* __restrict__ M0c,
    const float* __restrict__ Wv1, const float* __restrict__ Wo1,
    ushort* __restrict__ M1a, ushort* __restrict__ M1b, ushort* __restrict__ M1c,
    const float* __restrict__ W1, ushort* __restrict__ W1hi, ushort* __restrict__ W1lo,
    const float* __restrict__ W2, ushort* __restrict__ W2hi, ushort* __restrict__ W2lo,
    unsigned long long* __restrict__ out64)
{
  int blk = blockIdx.x, t = threadIdx.x;
  if (blk == 0) {
    if (t >= 32) return;
    int l = t >> 4, h = (t >> 2) & 3, a = (t >> 1) & 1, b = t & 1;
    const float* Wq = l ? Wq1 : Wq0;
    const float* Wk = l ? Wk1 : Wk0;
    float acc = 0.f;
    for (int c = 0; c < 128; c++)
      acc += Wq[(h * 128 + c) * 2 + a] * Wk[(h * 128 + c) * 2 + b];
    G[t] = acc;
  } else if (blk < 97) {
    // folded M = Wv^T-contract-Wo, triple-split; 4 consecutive d per thread.
    int D, gidx;
    const float *Wv, *Wo;
    ushort *Ma, *Mb, *Mc;
    if (blk < 33) { D = DIN; gidx = (blk - 1) * 256 + t;  Wv = Wv0; Wo = Wo0; Ma = M0a; Mb = M0b; Mc = M0c; }
    else          { D = HID; gidx = (blk - 33) * 256 + t; Wv = Wv1; Wo = Wo1; Ma = M1a; Mb = M1b; Mc = M1c; }
    int o = gidx / D, rem = gidx - o * D;          // D groups of 4 per o-row
    int qD = D >> 2;
    int h = rem / qD, d0 = (rem - h * qD) * 4;
    const float* wv = Wv + (size_t)(h * 128) * D + d0;
    const float* wo = Wo + (size_t)o * 512 + h * 128;
    float ax = 0.f, ay = 0.f, az = 0.f, aw = 0.f;
    for (int c = 0; c < 128; c++) {
      float4 v = *(const float4*)&wv[(size_t)c * D];
      float w = wo[c];
      ax += v.x * w; ay += v.y * w; az += v.z * w; aw += v.w * w;
    }
    int idx = o * (4 * D) + h * D + d0;
    ushort4 ua, ub, uc;
    split3(ax, ua.x, ub.x, uc.x);
    split3(ay, ua.y, ub.y, uc.y);
    split3(az, ua.z, ub.z, uc.z);
    split3(aw, ua.w, ub.w, uc.w);
    *(ushort4*)&Ma[idx] = ua;
    *(ushort4*)&Mb[idx] = ub;
    *(ushort4*)&Mc[idx] = uc;
  } else if (blk < 193) {
    if (blk < 129) {
      int i = ((blk - 97) * 256 + t) * 4;          // 32768 = 256*128 elems
      float4 w = *(const float4*)&W1[i];
      ushort4 hi, lo;
      split1(w.x, hi.x, lo.x); split1(w.y, hi.y, lo.y);
      split1(w.z, hi.z, lo.z); split1(w.w, hi.w, lo.w);
      *(ushort4*)&W1hi[i] = hi;
      *(ushort4*)&W1lo[i] = lo;
    } else {
      int j = ((blk - 129) * 256 + t) * 4;         // 65536 = 256*256 elems
      float4 w = *(const float4*)&W2[j];
      ushort4 hi, lo;
      split1(w.x, hi.x, lo.x); split1(w.y, hi.y, lo.y);
      split1(w.z, hi.z, lo.z); split1(w.w, hi.w, lo.w);
      *(ushort4*)&W2hi[j] = hi;
      *(ushort4*)&W2lo[j] = lo;
    }
  } else {
    int i = (blk - 193) * 256 + t;                 // 8192 float4 = 16384 u64
    ((float4*)out64)[i] = (float4){0.f, 0.f, 0.f, 0.f};
  }
}

// ---------------- fully fused: mask build + 2-layer GAT + 3-layer MLP ----------------
// R22: fixes R21's rule-#20 violation. R21 wrote the LDS-bounce redistribute
// as "#pragma unroll 1 for(kb){ y[2*kb+tt] }" -- runtime kb made y[] runtime-
// indexed -> scratch allocation (WRITE 16->67MB, VALUBusy 77%, 288us). The
// kb loop is now FULLY UNROLLED (all y[] indices compile-time); the compiler's
// memory-dependence analysis preserves the write->read->write->read order on
// the reused yT addresses (same provable offsets). Everything else identical
// to R21: wave-private yT bounce replaces 32 ds_bpermute + 16 selects per
// head; R20's balanced ship/combine kept. Bit-identical math.

// LDS layout (ushort offsets), total 74240 ushorts = 148480 B:
//  sFa 0 | sFb 8192 | sFc 16384   (64x128 each, swizzled)
//  pxs 24576 (f32[64]) | pys 24704 (f32[64]) | smask 24832 (u64[64])
//  aA 25088 (32768 ushorts = 64KB, 16 A-frag pairs)   [MLP: pA=aA, pB=aA+16384]
//  PART 57856 (16384 ushorts = 32KB: 16 blocks x 512 f32; per-wave yT slice
//              during gat_layer, pair-exchange slots at layer boundaries)
#define SFB_OFF 8192
#define SFC_OFF 16384
#define PXS_OFF 24576
#define PYS_OFF 24704
#define SMASK_OFF 24832
#define AFRAG_OFF 25088
#define PART_OFF 57856
#define LDS_USHORTS 74240

// A-build for one (h,mtd) pair: wave-agnostic (lane x pairid only).
__device__ __forceinline__ void build_A(
    int pairid, int lane, int lm, int lq, ushort* aA,
    const float* pxs, const float* pys,
    const unsigned long long* smask, const float* __restrict__ G)
{
  int wm = pairid & 3;
  int h = pairid >> 2;
  float pdxm = pxs[wm * 16 + lm];
  float pdym = pys[wm * 16 + lm];
  unsigned long long mm = smask[wm * 16 + lm];
  unsigned mb0 = (unsigned)((mm >> (8 * lq)) & 0xFF);
  unsigned mb1 = (unsigned)((mm >> (32 + 8 * lq)) & 0xFF);
  float g0 = G[h * 4], g1 = G[h * 4 + 1], g2 = G[h * 4 + 2], g3 = G[h * 4 + 3];
  float a0 = (g0 * pdxm + g2 * pdym) * SCALE_F;
  float a1 = (g1 * pdxm + g3 * pdym) * SCALE_F;
  float sshift = a0 * pdxm + a1 * pdym;
  float e[16];
  float sum = 0.f;
#pragma unroll
  for (int j = 0; j < 8; j++) {
    e[j]     = ((mb0 >> j) & 1) ? __expf(a0 * pxs[8 * lq + j] + a1 * pys[8 * lq + j] - sshift) : 0.f;
    e[8 + j] = ((mb1 >> j) & 1) ? __expf(a0 * pxs[32 + 8 * lq + j] + a1 * pys[32 + 8 * lq + j] - sshift) : 0.f;
    sum += e[j] + e[8 + j];
  }
  sum += __shfl_xor(sum, 16);
  sum += __shfl_xor(sum, 32);
  float inv = 1.f / sum;
  bf16x8 Aa0, Aa1, Ab0, Ab1;
#pragma unroll
  for (int j = 0; j < 8; j++) {
    ushort ua, ub;
    split1(e[j] * inv, ua, ub);     Aa0[j] = (short)ua; Ab0[j] = (short)ub;
    split1(e[8 + j] * inv, ua, ub); Aa1[j] = (short)ua; Ab1[j] = (short)ub;
  }
  int sbase = pairid * 2048 + lane * 8;
  *(bf16x8*)&aA[sbase]        = Aa0;
  *(bf16x8*)&aA[sbase + 512]  = Aa1;
  *(bf16x8*)&aA[sbase + 1024] = Ab0;
  *(bf16x8*)&aA[sbase + 1536] = Ab1;
}

template <int KD, bool BUILD_A>
__device__ __forceinline__ void gat_layer(
    int wave, int lane, int lm, int lq,
    const ushort* sFa, const ushort* sFb, const ushort* sFc,
    ushort* aA, float* yT,
    const float* pxs, const float* pys,
    const unsigned long long* smask,
    const float* __restrict__ G,
    const ushort* __restrict__ Ma, const ushort* __restrict__ Mb,
    const ushort* __restrict__ Mc,
    bf16x8 nA, bf16x8 nB, bf16x8 nC,    // prologue M triple (hoisted by caller)
    f32x4 hacc[4])
{
  constexpr int NKF = KD / 32;
  const int K4 = 4 * KD;
  const int o = 16 * (wave & 7) + lm;
  const int hb = wave >> 3;

  if (BUILD_A) {
    // layer-0 path: every wave builds its own pair, then barrier.
    build_A(wave, lane, lm, lq, aA, pxs, pys, smask, G);
    __syncthreads();   // BA: all 16 pairs' A-frags visible
  }
  // layer-1 path (BUILD_A=false): A-frags were built in the B3->B4 window
  // (1 pair per wave); caller's B4 barrier provides write->read ordering.

#pragma unroll
  for (int i = 0; i < 4; i++) hacc[i] = (f32x4){0.f, 0.f, 0.f, 0.f};

#pragma unroll 1
  for (int hi = 0; hi < 2; hi++) {
    int h = 2 * hb + hi;     // waves 0-7: heads {0,1}; waves 8-15: heads {2,3}
    f32x4 y[4];
#pragma unroll
    for (int i = 0; i < 4; i++) y[i] = (f32x4){0.f, 0.f, 0.f, 0.f};
#pragma unroll 1
    for (int kf = 0; kf < NKF; kf++) {
      int ko = kf * 32 + lq * 8;
      int sw = lm << 3;
      bf16x8 ma = nA, mb = nB, mc = nC;   // consume current triple
#pragma unroll
      for (int mp = 0; mp < 2; mp++) {
        int f0 = (mp * 32 + lm) * 128 + (ko ^ sw);
        int f1 = f0 + 16 * 128;
        bf16x8 fa0 = *(const bf16x8*)&sFa[f0], fa1 = *(const bf16x8*)&sFa[f1];
        bf16x8 fb0 = *(const bf16x8*)&sFb[f0], fb1 = *(const bf16x8*)&sFb[f1];
        bf16x8 fc0 = *(const bf16x8*)&sFc[f0], fc1 = *(const bf16x8*)&sFc[f1];
        f32x4 y0 = y[mp * 2], y1 = y[mp * 2 + 1];
        MFMA(y0, fa0, ma); MFMA(y1, fa1, ma);
        MFMA(y0, fa0, mb); MFMA(y1, fa1, mb);
        MFMA(y0, fb0, ma); MFMA(y1, fb1, ma);
        MFMA(y0, fa0, mc); MFMA(y1, fa1, mc);
        MFMA(y0, fc0, ma); MFMA(y1, fc1, ma);
        MFMA(y0, fb0, mb); MFMA(y1, fb1, mb);
        y[mp * 2] = y0; y[mp * 2 + 1] = y1;
      }
      // refill: next kf of this head, or kf=0 of head h+1 (skip at very end).
      if (hi == 0 || kf != NKF - 1) {
        int hn = (kf == NKF - 1) ? (h + 1) : h;
        int kn = (kf == NKF - 1) ? 0 : (kf + 1);
        size_t boff = (size_t)o * K4 + hn * KD + kn * 32 + lq * 8;
        nA = *(const bf16x8*)&Ma[boff];
        nB = *(const bf16x8*)&Mb[boff];
        nC = *(const bf16x8*)&Mc[boff];
      }
    }
    // redistribute y (C-layout) -> B-frag values via wave-private LDS bounce.
    // FULLY UNROLLED (R22): all y[] indices compile-time (rule #20). The
    // kb=1 writes reuse kb=0's addresses; compiler memory-dependence keeps
    // write->read->write->read order. XOR swizzle (4-word) keeps accesses
    // <=2-way bank-aliased (free per m136).
    bf16x8 Ya[2], Yb[2];
    int swz = (lm & 7) << 2;
    int wb = lm * 32;
#pragma unroll
    for (int kb = 0; kb < 2; kb++) {
      *(float4*)&yT[wb + ((lq * 4) ^ swz)]      = *(float4*)&y[2 * kb];
      *(float4*)&yT[wb + ((16 + lq * 4) ^ swz)] = *(float4*)&y[2 * kb + 1];
      float4 r0 = *(const float4*)&yT[wb + ((lq * 8) ^ swz)];
      float4 r1 = *(const float4*)&yT[wb + ((lq * 8 + 4) ^ swz)];
      float rv[8] = {r0.x, r0.y, r0.z, r0.w, r1.x, r1.y, r1.z, r1.w};
#pragma unroll
      for (int j = 0; j < 8; j++) {
        ushort ua, ub;
        split1(rv[j], ua, ub);
        Ya[kb][j] = (short)ua; Yb[kb][j] = (short)ub;
      }
    }
    // A@Y per dst tile, A-frags from LDS (lane-linear b128, conflict-free)
#pragma unroll
    for (int mtd = 0; mtd < 4; mtd++) {
      int abase = (h * 4 + mtd) * 2048 + lane * 8;
      bf16x8 Aa0 = *(const bf16x8*)&aA[abase];
      bf16x8 Aa1 = *(const bf16x8*)&aA[abase + 512];
      bf16x8 Ab0 = *(const bf16x8*)&aA[abase + 1024];
      bf16x8 Ab1 = *(const bf16x8*)&aA[abase + 1536];
      MFMA(hacc[mtd], Aa0, Ya[0]);
      MFMA(hacc[mtd], Aa0, Yb[0]);
      MFMA(hacc[mtd], Ab0, Ya[0]);
      MFMA(hacc[mtd], Ab0, Yb[0]);
      MFMA(hacc[mtd], Aa1, Ya[1]);
      MFMA(hacc[mtd], Aa1, Yb[1]);
      MFMA(hacc[mtd], Ab1, Ya[1]);
      MFMA(hacc[mtd], Ab1, Yb[1]);
    }
  }
}

__global__ __attribute__((amdgpu_flat_work_group_size(1024, 1024), amdgpu_waves_per_eu(4, 4)))
void fused_gat_kernel(
    const float* __restrict__ x, const float* __restrict__ pos,
    const int* __restrict__ srcp, const int* __restrict__ dstp,
    const float* __restrict__ G,
    const ushort* __restrict__ M0a, const ushort* __restrict__ M0b, const ushort* __restrict__ M0c,
    const ushort* __restrict__ M1a, const ushort* __restrict__ M1b, const ushort* __restrict__ M1c,
    const float* __restrict__ bo0, const float* __restrict__ bo1,
    const ushort* __restrict__ W1hi, const ushort* __restrict__ W1lo, const float* __restrict__ b1,
    const ushort* __restrict__ W2hi, const ushort* __restrict__ W2lo, const float* __restrict__ b2,
    const float* __restrict__ W3, const float* __restrict__ b3,
    float* __restrict__ outp)
{
  __shared__ __align__(16) ushort uBig[LDS_USHORTS];
  ushort* sFa = uBig;
  ushort* sFb = uBig + SFB_OFF;
  ushort* sFc = uBig + SFC_OFF;
  float* pxs = (float*)(uBig + PXS_OFF);
  float* pys = (float*)(uBig + PYS_OFF);
  unsigned long long* smask = (unsigned long long*)(uBig + SMASK_OFF);
  ushort* aA = uBig + AFRAG_OFF;
  ushort* pA = uBig + AFRAG_OFF;            // MLP reuse of A region (dead by then)
  ushort* pB = uBig + AFRAG_OFF + 16384;
  float* part = (float*)(uBig + PART_OFF);  // 16 x 512-f32 wave blocks

  int b = blockIdx.x, t = threadIdx.x;
  int wave = t >> 6, lane = t & 63, lm = lane & 15, lq = lane >> 4;
  int o = 16 * (wave & 7) + lm;

  // per-wave block (yT slice == own exchange slot); partner block for reads
  int half = wave >> 3;
  float* yT = part + (2 * (wave & 7) + half) * 512;
  const float* pT = part + (2 * (wave & 7) + (1 - half)) * 512;

  // ---- hoisted global loads: edges, pos, x, biases, layer-0 M prologue ----
  int e_s = 0, e_d = 0;
  if (t < 448) {
    e_s = srcp[b * 448 + t];
    e_d = dstp[b * 448 + t];
  }
  float posx = 0.f, posy = 0.f;
  if (t < 64) {
    posx = pos[(b * 64 + t) * 2];
    posy = pos[(b * 64 + t) * 2 + 1];
  }
  const float4* gx = (const float4*)(x + (size_t)b * 64 * DIN);
  float4 xv = gx[t];
  float bv0 = bo0[o];
  float bv1 = bo1[o];
  // layer-0 M prologue triple (head 2*half, kf 0); in flight across
  // X-staging + B1 + mask + B2 + A-build.
  bf16x8 m0A, m0B, m0C;
  {
    size_t boff = (size_t)o * (4 * DIN) + (half * 2) * DIN + lq * 8;
    m0A = *(const bf16x8*)&M0a[boff];
    m0B = *(const bf16x8*)&M0b[boff];
    m0C = *(const bf16x8*)&M0c[boff];
  }

  if (t < 64) {
    pxs[t] = posx;
    pys[t] = posy;
    smask[t] = 1ull << t;   // self-loop bit
  }
  // stage X (64x64 fp32) -> triple-split swizzled planes; one float4/thread
  {
    int r = t >> 4, c = (t & 15) * 4;
    int cs = c ^ ((r & 15) << 3);
    ushort4 ua, ub, uc;
    split3(xv.x, ua.x, ub.x, uc.x); split3(xv.y, ua.y, ub.y, uc.y);
    split3(xv.z, ua.z, ub.z, uc.z); split3(xv.w, ua.w, ub.w, uc.w);
    *(ushort4*)&sFa[r * 128 + cs] = ua;
    *(ushort4*)&sFb[r * 128 + cs] = ub;
    *(ushort4*)&sFc[r * 128 + cs] = uc;
  }
  __syncthreads();   // B1: smask init + X visible
  // adjacency from this block's own 448 kNN edge rows (loads hoisted to top)
  if (t < 448) {
    atomicOr(&smask[e_d & 63], 1ull << (e_s & 63));
  }
  __syncthreads();   // B2

  f32x4 hacc[4];
  gat_layer<DIN, true>(wave, lane, lm, lq, sFa, sFb, sFc, aA, yT, pxs, pys,
                       smask, G, M0a, M0b, M0c, m0A, m0B, m0C, hacc);

  // layer-1 M prologue; in flight across exchange / B3 / combine / B4
  bf16x8 m1A, m1B, m1C;
  {
    size_t boff = (size_t)o * (4 * HID) + (half * 2) * HID + lq * 8;
    m1A = *(const bf16x8*)&M1a[boff];
    m1B = *(const bf16x8*)&M1b[boff];
    m1C = *(const bf16x8*)&M1c[boff];
  }

  // ship the 2 dst-tiles the partner combines (b128 each, own block)
  if (wave < 8) {
    *(float4*)&yT[lane * 4]       = *(float4*)&hacc[2];
    *(float4*)&yT[lane * 4 + 256] = *(float4*)&hacc[3];
  } else {
    *(float4*)&yT[lane * 4]       = *(float4*)&hacc[0];
    *(float4*)&yT[lane * 4 + 256] = *(float4*)&hacc[1];
  }
  __syncthreads();   // B3: layer-0 F/A reads done + partials visible
  {
    // balanced combine: every wave activates 2 dst-tiles + builds 1 layer-1
    // A-pair. Sum order: own + partner == commutative swap -> bit-identical.
    float4 q0 = *(const float4*)&pT[lane * 4];
    float4 q1 = *(const float4*)&pT[lane * 4 + 256];
    float pr0[4] = {q0.x, q0.y, q0.z, q0.w};
    float pr1[4] = {q1.x, q1.y, q1.z, q1.w};
    if (wave < 8) {
#pragma unroll
      for (int r = 0; r < 4; r++) {
        int d0 = lq * 4 + r;
        float v = tanhf(hacc[0][r] + pr0[r] + bv0);
        ushort ua, ub, uc;
        split3(v, ua, ub, uc);
        int cs = o ^ ((d0 & 15) << 3);
        sFa[d0 * 128 + cs] = ua; sFb[d0 * 128 + cs] = ub; sFc[d0 * 128 + cs] = uc;
        int d1 = 16 + lq * 4 + r;
        v = tanhf(hacc[1][r] + pr1[r] + bv0);
        split3(v, ua, ub, uc);
        sFa[d1 * 128 + cs] = ua; sFb[d1 * 128 + cs] = ub; sFc[d1 * 128 + cs] = uc;
      }
    } else {
#pragma unroll
      for (int r = 0; r < 4; r++) {
        int d2 = 32 + lq * 4 + r;
        float v = tanhf(hacc[2][r] + pr0[r] + bv0);
        ushort ua, ub, uc;
        split3(v, ua, ub, uc);
        int cs = o ^ ((d2 & 15) << 3);
        sFa[d2 * 128 + cs] = ua; sFb[d2 * 128 + cs] = ub; sFc[d2 * 128 + cs] = uc;
        int d3 = 48 + lq * 4 + r;
        v = tanhf(hacc[3][r] + pr1[r] + bv0);
        split3(v, ua, ub, uc);
        sFa[d3 * 128 + cs] = ua; sFb[d3 * 128 + cs] = ub; sFc[d3 * 128 + cs] = uc;
      }
    }
    build_A(wave, lane, lm, lq, aA, pxs, pys, smask, G + 16);
  }
  __syncthreads();   // B4: h1 planes + layer-1 A-frags visible
  gat_layer<HID, false>(wave, lane, lm, lq, sFa, sFb, sFc, aA, yT, pxs, pys,
                        smask, G + 16, M1a, M1b, M1c, m1A, m1B, m1C, hacc);

  // prefetch W1 frags + b1 now; in flight across exchange / B5 / combine / B6
  int col = 16 * wave + lm;
  bf16x8 pw1h[4], pw1l[4];
#pragma unroll
  for (int kf = 0; kf < 4; kf++) {
    int ko = kf * 32 + lq * 8;
    pw1h[kf] = *(const bf16x8*)&W1hi[(size_t)col * 128 + ko];
    pw1l[kf] = *(const bf16x8*)&W1lo[(size_t)col * 128 + ko];
  }
  float b1v = b1[col];

  if (wave < 8) {
    *(float4*)&yT[lane * 4]       = *(float4*)&hacc[2];
    *(float4*)&yT[lane * 4 + 256] = *(float4*)&hacc[3];
  } else {
    *(float4*)&yT[lane * 4]       = *(float4*)&hacc[0];
    *(float4*)&yT[lane * 4 + 256] = *(float4*)&hacc[1];
  }
  __syncthreads();   // B5
  {
    float4 q0 = *(const float4*)&pT[lane * 4];
    float4 q1 = *(const float4*)&pT[lane * 4 + 256];
    float pr0[4] = {q0.x, q0.y, q0.z, q0.w};
    float pr1[4] = {q1.x, q1.y, q1.z, q1.w};
    if (wave < 8) {
#pragma unroll
      for (int r = 0; r < 4; r++) {
        int d0 = lq * 4 + r;
        float v = tanhf(hacc[0][r] + pr0[r] + bv1);
        ushort hh, ll;
        split1(v, hh, ll);
        int cs = o ^ ((d0 & 15) << 3);
        sFa[d0 * 128 + cs] = hh; sFb[d0 * 128 + cs] = ll;
        int d1 = 16 + lq * 4 + r;
        v = tanhf(hacc[1][r] + pr1[r] + bv1);
        split1(v, hh, ll);
        sFa[d1 * 128 + cs] = hh; sFb[d1 * 128 + cs] = ll;
      }
    } else {
#pragma unroll
      for (int r = 0; r < 4; r++) {
        int d2 = 32 + lq * 4 + r;
        float v = tanhf(hacc[2][r] + pr0[r] + bv1);
        ushort hh, ll;
        split1(v, hh, ll);
        int cs = o ^ ((d2 & 15) << 3);
        sFa[d2 * 128 + cs] = hh; sFb[d2 * 128 + cs] = ll;
        int d3 = 48 + lq * 4 + r;
        v = tanhf(hacc[3][r] + pr1[r] + bv1);
        split1(v, hh, ll);
        sFa[d3 * 128 + cs] = hh; sFb[d3 * 128 + cs] = ll;
      }
    }
  }
  __syncthreads();   // B6
  // ---- W1: out1 = relu(h2 @ W1^T + b1); 16 waves x 16 cols ----
  f32x4 y1[4];
#pragma unroll
  for (int mtd = 0; mtd < 4; mtd++) y1[mtd] = (f32x4){0.f, 0.f, 0.f, 0.f};
#pragma unroll
  for (int kf = 0; kf < 4; kf++) {
    int ko = kf * 32 + lq * 8;
    bf16x8 bh = pw1h[kf];
    bf16x8 bl = pw1l[kf];
#pragma unroll
    for (int mtd = 0; mtd < 4; mtd++) {
      int row = mtd * 16 + lm;
      int cs = ko ^ (lm << 3);
      bf16x8 ah = *(const bf16x8*)&sFa[row * 128 + cs];
      bf16x8 al = *(const bf16x8*)&sFb[row * 128 + cs];
      MFMA(y1[mtd], ah, bh);
      MFMA(y1[mtd], ah, bl);
      MFMA(y1[mtd], al, bh);
    }
  }
  // store out1 split2, XOR-swizzled: elem (row,k) at row*256 + (k ^ ((row&15)<<3))
  {
#pragma unroll
    for (int mtd = 0; mtd < 4; mtd++)
#pragma unroll
      for (int r = 0; r < 4; r++) {
        int row = mtd * 16 + lq * 4 + r;
        float v = fmaxf(y1[mtd][r] + b1v, 0.f);
        ushort hh, ll;
        split1(v, hh, ll);
        int cc = col ^ ((row & 15) << 3);
        pA[row * 256 + cc] = hh;
        pB[row * 256 + cc] = ll;
      }
  }
  // prefetch W2 frags + W3/b2 scalars; in flight across B8
  bf16x8 pw2h[8], pw2l[8];
#pragma unroll
  for (int kf = 0; kf < 8; kf++) {
    int ko = kf * 32 + lq * 8;
    pw2h[kf] = *(const bf16x8*)&W2hi[(size_t)col * 256 + ko];
    pw2l[kf] = *(const bf16x8*)&W2lo[(size_t)col * 256 + ko];
  }
  float w30 = W3[col], w31 = W3[256 + col];
  float b20 = b2[col];
  float bb0 = (wave == 0) ? b3[0] : 0.f;
  float bb1 = (wave == 0) ? b3[1] : 0.f;
  __syncthreads();   // B8
  // ---- W2 + fused W3 ----
  f32x4 y2[4];
#pragma unroll
  for (int mtd = 0; mtd < 4; mtd++) y2[mtd] = (f32x4){0.f, 0.f, 0.f, 0.f};
#pragma unroll
  for (int kf = 0; kf < 8; kf++) {
    int ko = kf * 32 + lq * 8;
    bf16x8 bh = pw2h[kf];
    bf16x8 bl = pw2l[kf];
#pragma unroll
    for (int mtd = 0; mtd < 4; mtd++) {
      int row = mtd * 16 + lm;
      int cc = ko ^ (lm << 3);
      bf16x8 ah = *(const bf16x8*)&pA[row * 256 + cc];
      bf16x8 al = *(const bf16x8*)&pB[row * 256 + cc];
      MFMA(y2[mtd], ah, bh);
      MFMA(y2[mtd], ah, bl);
      MFMA(y2[mtd], al, bh);
    }
  }
  // W3 epilogue: per-row dot over this wave's 16 cols, lm-reduce, atomicAdd
  {
#pragma unroll
    for (int mtd = 0; mtd < 4; mtd++)
#pragma unroll
      for (int r = 0; r < 4; r++) {
        float va = fmaxf(y2[mtd][r] + b20, 0.f);
        float s0 = va * w30;
        float s1 = va * w31;
        s0 += __shfl_xor(s0, 1); s0 += __shfl_xor(s0, 2);
        s0 += __shfl_xor(s0, 4); s0 += __shfl_xor(s0, 8);
        s1 += __shfl_xor(s1, 1); s1 += __shfl_xor(s1, 2);
        s1 += __shfl_xor(s1, 4); s1 += __shfl_xor(s1, 8);
        if (lm == 0) {
          int row = b * 64 + mtd * 16 + lq * 4 + r;
          atomicAdd(&outp[row * 2 + 0], s0 + bb0);
          atomicAdd(&outp[row * 2 + 1], s1 + bb1);
        }
      }
  }
}

// ---------------- launch ----------------

extern "C" void kernel_launch(void* const* d_in, const int* in_sizes, int n_in,
                              void* d_out, int out_size, void* d_ws, size_t ws_size,
                              hipStream_t stream) {
  const float* x     = (const float*)d_in[0];
  const float* pos   = (const float*)d_in[1];
  const int*   ei    = (const int*)d_in[2];
  const float* l0_Wq = (const float*)d_in[3];
  const float* l0_Wk = (const float*)d_in[4];
  const float* l0_Wv = (const float*)d_in[5];
  const float* l0_Wo = (const float*)d_in[6];
  const float* l0_bo = (const float*)d_in[7];
  const float* l1_Wq = (const float*)d_in[8];
  const float* l1_Wk = (const float*)d_in[9];
  const float* l1_Wv = (const float*)d_in[10];
  const float* l1_Wo = (const float*)d_in[11];
  const float* l1_bo = (const float*)d_in[12];
  const float* W1    = (const float*)d_in[13];
  const float* b1    = (const float*)d_in[14];
  const float* W2    = (const float*)d_in[15];
  const float* b2    = (const float*)d_in[16];
  const float* W3    = (const float*)d_in[17];
  const float* b3    = (const float*)d_in[18];
  float* outp = (float*)d_out;

  int E = in_sizes[2] / 2;
  const int* srcp = ei;
  const int* dstp = ei + E;

  char* base = (char*)d_ws;
  size_t off = 0;
  auto alloc = [&](size_t bytes) -> void* {
    void* p = base + off;
    off = (off + bytes + 255) & ~(size_t)255;
    return p;
  };
  float*  G   = (float*)alloc(32 * sizeof(float));
  ushort* M0a = (ushort*)alloc((size_t)128 * 256 * 2);
  ushort* M0b = (ushort*)alloc((size_t)128 * 256 * 2);
  ushort* M0c = (ushort*)alloc((size_t)128 * 256 * 2);
  ushort* M1a = (ushort*)alloc((size_t)128 * 512 * 2);
  ushort* M1b = (ushort*)alloc((size_t)128 * 512 * 2);
  ushort* M1c = (ushort*)alloc((size_t)128 * 512 * 2);
  ushort* W1hi = (ushort*)alloc((size_t)256 * 128 * 2);
  ushort* W1lo = (ushort*)alloc((size_t)256 * 128 * 2);
  ushort* W2hi = (ushort*)alloc((size_t)256 * 256 * 2);
  ushort* W2lo = (ushort*)alloc((size_t)256 * 256 * 2);

  // prep: G, M folds (4-wide vectorized), W splits, zero(out). Grid 225.
  prep_all_kernel<<<225, 256, 0, stream>>>(
      l0_Wq, l0_Wk, l1_Wq, l1_Wk, G,
      l0_Wv, l0_Wo, M0a, M0b, M0c,
      l1_Wv, l1_Wo, M1a, M1b, M1c,
      W1, W1hi, W1lo, W2, W2hi, W2lo,
      (unsigned long long*)outp);

  // fully fused network: 1024 threads (16 waves), head-split halves
  fused_gat_kernel<<<N_NODES / 64, 1024, 0, stream>>>(
      x, pos, srcp, dstp, G, M0a, M0b, M0c, M1a, M1b, M1c, l0_bo, l1_bo,
      W1hi, W1lo, b1, W2hi, W2lo, b2, W3, b3, outp);

  (void)n_in; (void)out_size; (void)ws_size;
}